// Round 7
// baseline (47.526 us; speedup 1.0000x reference)
//
#include <hip/hip_runtime.h>

// out[b,s,h,w] = sum_t input[b,s,t,h,w] * weight[t, h%8, w%8]   (h,w < 256; else 0)
// output[b, s*1024 + i*32 + j, q*16 + p] = out[b,s, 8i+p, 8j+q]   i,j in [0,32), p,q in [0,16)
//
// Round-7: full-width row geometry. Block = (b, s, ig in 0..15): window rows
// i = 2*ig, 2*ig+1, ALL 32 window cols. Region rows [16*ig, 16*ig+24) x cols [0,264).
// Phase-1 wave mapping: wave -> one region row r, lane -> 16B column chunk, so each
// per-t global load is ONE aligned contiguous 1KB burst (64 lanes x float4 = a full
// 256-float image row). Halo cols 256..263 are zero-filled without loads.
// 512 blocks x 512 threads -> 2 blocks/CU, 16 waves/CU. Plain stores (R5: nt stores
// caused 2.6x WRITE amplification). XCD swizzle: one b (64 blocks) per XCD.

namespace {

constexpr int TT    = 16;
constexpr int RROWS = 24;    // 2*8 + 8 halo
constexpr int LDSW  = 268;   // 264 cols + 4 pad: float4-aligned rows, 12-bank row skew

__global__ __launch_bounds__(512, 4) void meas_kernel(
    const float* __restrict__ in, const float* __restrict__ wt,
    float* __restrict__ out)
{
    __shared__ float tile[RROWS * LDSW];
    __shared__ float wlds[TT * 64];

    const int tid = threadIdx.x;
    for (int idx = tid; idx < TT * 64; idx += 512) wlds[idx] = wt[idx];

    // zero the halo columns (cols 256..263 = c4 slots 64,65 of each row): 48 float4 slots
    if (tid < 48) {
        const int r  = tid >> 1;
        const int c4 = 64 + (tid & 1);
        *reinterpret_cast<float4*>(&tile[r * LDSW + c4 * 4]) =
            make_float4(0.f, 0.f, 0.f, 0.f);
    }

    // XCD swizzle: 512 blocks, 8 XCDs -> 64 logical blocks (one b) per XCD.
    // Logical bits: b(6..8) | s(4..5) | ig(0..3) -> ig-neighbors (shared halo rows) co-XCD.
    const int bid = (blockIdx.x & 7) * 64 + (blockIdx.x >> 3);
    const int ig = bid & 15;
    const int s  = (bid >> 4) & 3;
    const int b  = bid >> 6;

    const int i0 = ig * 2;      // first window row
    const int h0 = ig * 16;     // region row origin

    const float* __restrict__ inp = in + (size_t)(b * 4 + s) * TT * 65536;
    float* __restrict__ outb = out + ((size_t)b * 4096 + (size_t)s * 1024) * 256;

    __syncthreads();   // weights + halo zeros visible

    // ---- Phase 1: compute 24 rows x 256 cols into LDS ----
    // slot = m*512 + tid ; r = slot>>6 (wave-uniform), lane c = slot&63 -> w = 4c.
    // Per t: one aligned 1KB contiguous wave load.
#pragma unroll
    for (int m = 0; m < 3; ++m) {
        const int slot = m * 512 + tid;
        const int r = slot >> 6;
        const int c = slot & 63;
        const int h = h0 + r;
        const int w = c * 4;
        float4 acc = make_float4(0.f, 0.f, 0.f, 0.f);
        if (h < 256) {
            const float* wrow = &wlds[(h & 7) * 8 + (w & 7)];
            const float* gp   = inp + h * 256 + w;
#pragma unroll
            for (int t = 0; t < TT; ++t) {
                const float4 v  = *reinterpret_cast<const float4*>(gp + t * 65536);
                const float4 wv = *reinterpret_cast<const float4*>(wrow + t * 64);
                acc.x += v.x * wv.x;
                acc.y += v.y * wv.y;
                acc.z += v.z * wv.z;
                acc.w += v.w * wv.w;
            }
        }
        *reinterpret_cast<float4*>(&tile[r * LDSW + w]) = acc;
    }

    __syncthreads();

    // ---- Phase 2: store 64 windows (2 window-rows x 32 cols), coalesced 1KB bursts ----
    // k = 4*lane + jj : p = (lane&3)*4 + jj, q = lane>>2
    const int wave = tid >> 6;   // 0..7
    const int lane = tid & 63;
    const int p0 = (lane & 3) * 4;
    const int q  = lane >> 2;

#pragma unroll
    for (int m = 0; m < 8; ++m) {
        const int widx = wave + 8 * m;        // 0..63
        const int di = widx >> 5;             // 0..1
        const int dj = widx & 31;             // 0..31
        const float* src = &tile[(di * 8 + p0) * LDSW + dj * 8 + q];
        const int n = (i0 + di) * 32 + dj;
        *reinterpret_cast<float4*>(outb + (size_t)n * 256 + lane * 4) =
            make_float4(src[0 * LDSW], src[1 * LDSW], src[2 * LDSW], src[3 * LDSW]);
    }
}

} // namespace

extern "C" void kernel_launch(void* const* d_in, const int* in_sizes, int n_in,
                              void* d_out, int out_size, void* d_ws, size_t ws_size,
                              hipStream_t stream) {
    const float* in = (const float*)d_in[0];
    const float* wt = (const float*)d_in[1];
    float* out      = (float*)d_out;
    hipLaunchKernelGGL(meas_kernel, dim3(512), dim3(512), 0, stream, in, wt, out);
}

// Round 8
// 44.110 us; speedup vs baseline: 1.0775x; 1.0775x over previous
//
#include <hip/hip_runtime.h>

// out[b,s,h,w] = sum_t input[b,s,t,h,w] * weight[t, h%8, w%8]   (h,w < 256; else 0)
// output[b, s*1024 + i*32 + j, q*16 + p] = out[b,s, 8i+p, 8j+q]   i,j in [0,32), p,q in [0,16)
//
// Round-8: R7 full-width row geometry + forced 16-deep load batching.
// R7 counters: VGPR=36, VALUBusy=2.2%, read BW 1.75 TB/s -> compiler serialized the
// t-loop (load->fma->load, <1 load in flight per wave). Fix: explicit float4 v[16]
// register batch: issue all 16 per-t 1KB wave bursts back-to-back, then FMA.
// Per-wave in-flight during wait = 16KB; 2 blocks/CU x 8 waves covers the ~9.2KB/CU
// needed for 6.3 TB/s.

namespace {

constexpr int TT    = 16;
constexpr int RROWS = 24;    // 2*8 + 8 halo
constexpr int LDSW  = 268;   // 264 cols + 4 pad: float4-aligned rows

__global__ __launch_bounds__(512, 4) void meas_kernel(
    const float* __restrict__ in, const float* __restrict__ wt,
    float* __restrict__ out)
{
    __shared__ float tile[RROWS * LDSW];
    __shared__ float wlds[TT * 64];

    const int tid = threadIdx.x;
    for (int idx = tid; idx < TT * 64; idx += 512) wlds[idx] = wt[idx];

    // zero the halo columns (cols 256..263 = c4 slots 64,65 of each row)
    if (tid < 48) {
        const int r  = tid >> 1;
        const int c4 = 64 + (tid & 1);
        *reinterpret_cast<float4*>(&tile[r * LDSW + c4 * 4]) =
            make_float4(0.f, 0.f, 0.f, 0.f);
    }

    // XCD swizzle: 512 blocks, 8 XCDs -> 64 logical blocks (one b) per XCD.
    const int bid = (blockIdx.x & 7) * 64 + (blockIdx.x >> 3);
    const int ig = bid & 15;
    const int s  = (bid >> 4) & 3;
    const int b  = bid >> 6;

    const int i0 = ig * 2;      // first window row
    const int h0 = ig * 16;     // region row origin

    const float* __restrict__ inp = in + (size_t)(b * 4 + s) * TT * 65536;
    float* __restrict__ outb = out + ((size_t)b * 4096 + (size_t)s * 1024) * 256;

    __syncthreads();   // weights + halo zeros visible

    // ---- Phase 1: compute 24 rows x 256 cols into LDS ----
    // slot = m*512 + tid ; r = slot>>6 (wave-uniform), lane c = slot&63 -> w = 4c.
    // Per t: one aligned contiguous 1KB wave burst.
#pragma unroll 1
    for (int m = 0; m < 3; ++m) {
        const int slot = m * 512 + tid;
        const int r = slot >> 6;
        const int c = slot & 63;
        const int h = h0 + r;
        const int w = c * 4;
        float4 acc = make_float4(0.f, 0.f, 0.f, 0.f);
        if (h < 256) {
            const float* gp = inp + h * 256 + w;
            // 1) issue all 16 strided 1KB bursts back-to-back (16KB/wave in flight)
            float4 v[TT];
#pragma unroll
            for (int t = 0; t < TT; ++t)
                v[t] = *reinterpret_cast<const float4*>(gp + t * 65536);
            // 2) FMA against LDS-resident weights
            const float* wrow = &wlds[(h & 7) * 8 + (w & 7)];
#pragma unroll
            for (int t = 0; t < TT; ++t) {
                const float4 wv = *reinterpret_cast<const float4*>(wrow + t * 64);
                acc.x += v[t].x * wv.x;
                acc.y += v[t].y * wv.y;
                acc.z += v[t].z * wv.z;
                acc.w += v[t].w * wv.w;
            }
        }
        *reinterpret_cast<float4*>(&tile[r * LDSW + w]) = acc;
    }

    __syncthreads();

    // ---- Phase 2: store 64 windows (2 window-rows x 32 cols), 1KB bursts ----
    // k = 4*lane + jj : p = (lane&3)*4 + jj, q = lane>>2
    const int wave = tid >> 6;   // 0..7
    const int lane = tid & 63;
    const int p0 = (lane & 3) * 4;
    const int q  = lane >> 2;

#pragma unroll
    for (int m = 0; m < 8; ++m) {
        const int widx = wave + 8 * m;        // 0..63
        const int di = widx >> 5;             // 0..1
        const int dj = widx & 31;             // 0..31
        const float* src = &tile[(di * 8 + p0) * LDSW + dj * 8 + q];
        const int n = (i0 + di) * 32 + dj;
        *reinterpret_cast<float4*>(outb + (size_t)n * 256 + lane * 4) =
            make_float4(src[0 * LDSW], src[1 * LDSW], src[2 * LDSW], src[3 * LDSW]);
    }
}

} // namespace

extern "C" void kernel_launch(void* const* d_in, const int* in_sizes, int n_in,
                              void* d_out, int out_size, void* d_ws, size_t ws_size,
                              hipStream_t stream) {
    const float* in = (const float*)d_in[0];
    const float* wt = (const float*)d_in[1];
    float* out      = (float*)d_out;
    hipLaunchKernelGGL(meas_kernel, dim3(512), dim3(512), 0, stream, in, wt, out);
}

// Round 9
// 37.536 us; speedup vs baseline: 1.2662x; 1.1751x over previous
//
#include <hip/hip_runtime.h>

// out[b,s,h,w] = sum_t input[b,s,t,h,w] * weight[t, h%8, w%8]   (h,w < 256; else 0)
// output[b, s*1024 + i*32 + j, q*16 + p] = out[b,s, 8i+p, 8j+q]   i,j in [0,32), p,q in [0,16)
//
// Round-9: zero-halo scatter-write. Block (b,s,g), g in 0..15, owns image rows
// [16g,16g+16) DISJOINTLY (read amp 1.0; R6's 1.33x amp was the plateau cause:
// issued 212 MB @ 5.6 TB/s = 38us; this issues ~162 MB).
// Phase 1: t-sum of owned rows -> 16x268 LDS tile (16-deep batched 1KB row bursts,
//          no bounds checks).
// Phase 2: write all 4 window-memberships of owned pixels:
//   - full window-row i=2g            (p=0..15 <- local rows 0..15)
//   - upper half of row 2g+1 (p<8)    (<- local rows 8..15)
//   - lower half of row 2g-1 (p>=8)   (<- local rows 0..7), g>0
//   - g==15: zero-fill p>=8 half of window-row 31 (image rows 256.. = pad)
// Each output element written exactly once. Half-window stores are 32B lane-pair
// chunks; line partners written concurrently by the co-XCD neighbor block -> L2 merge.

namespace {

constexpr int TT   = 16;
constexpr int LDSW = 268;   // 264 cols + 4 pad

__global__ __launch_bounds__(512, 4) void meas_kernel(
    const float* __restrict__ in, const float* __restrict__ wt,
    float* __restrict__ out)
{
    __shared__ float tile[16 * LDSW];
    __shared__ float wlds[TT * 64];

    const int tid = threadIdx.x;
    for (int idx = tid; idx < TT * 64; idx += 512) wlds[idx] = wt[idx];

    // zero halo cols 256..263 (c4 slots 64,65) of the 16 tile rows
    if (tid < 32) {
        const int r  = tid >> 1;
        const int c4 = 64 + (tid & 1);
        *reinterpret_cast<float4*>(&tile[r * LDSW + c4 * 4]) =
            make_float4(0.f, 0.f, 0.f, 0.f);
    }

    // XCD swizzle: 512 blocks, 8 XCDs -> 64 logical blocks (one b) per XCD;
    // g-neighbors (who share output cache lines) are adjacent -> co-XCD, co-time.
    const int bid = (blockIdx.x & 7) * 64 + (blockIdx.x >> 3);
    const int g = bid & 15;
    const int s = (bid >> 4) & 3;
    const int b = bid >> 6;

    const float* __restrict__ inp = in + (size_t)(b * 4 + s) * TT * 65536;
    float* __restrict__ outb = out + ((size_t)b * 4096 + (size_t)s * 1024) * 256;

    __syncthreads();   // weights + halo zeros visible

    // ---- Phase 1: t-sum of rows [16g, 16g+16) into LDS ----
    // slot -> r = slot>>6 (wave-uniform), lane c -> w = 4c: per t one aligned
    // contiguous 1KB wave burst. All rows valid: no bounds checks.
#pragma unroll 1
    for (int m = 0; m < 2; ++m) {
        const int slot = m * 512 + tid;
        const int r = slot >> 6;      // 0..15
        const int c = slot & 63;
        const int h = g * 16 + r;
        const int w = c * 4;
        const float* gp = inp + h * 256 + w;
        float4 v[TT];
#pragma unroll
        for (int t = 0; t < TT; ++t)
            v[t] = *reinterpret_cast<const float4*>(gp + t * 65536);
        const float* wrow = &wlds[(h & 7) * 8 + (w & 7)];
        float4 acc = make_float4(0.f, 0.f, 0.f, 0.f);
#pragma unroll
        for (int t = 0; t < TT; ++t) {
            const float4 wv = *reinterpret_cast<const float4*>(wrow + t * 64);
            acc.x += v[t].x * wv.x;
            acc.y += v[t].y * wv.y;
            acc.z += v[t].z * wv.z;
            acc.w += v[t].w * wv.w;
        }
        *reinterpret_cast<float4*>(&tile[r * LDSW + w]) = acc;
    }

    __syncthreads();

    const int wave = tid >> 6;   // 0..7
    const int lane = tid & 63;

    // ---- Phase 2a: full window-row i = 2g (32 windows, 1KB bursts) ----
    // k = 4*lane + jj : p = (lane&3)*4 + jj, q = lane>>2 ; lane*4 == q*16+p0
    {
        const int p0 = (lane & 3) * 4;
        const int q  = lane >> 2;
#pragma unroll
        for (int mm = 0; mm < 4; ++mm) {
            const int j = wave + 8 * mm;                    // 0..31
            const float* src = &tile[p0 * LDSW + j * 8 + q];
            const int n = 64 * g + j;
            *reinterpret_cast<float4*>(outb + (size_t)n * 256 + lane * 4) =
                make_float4(src[0], src[LDSW], src[2 * LDSW], src[3 * LDSW]);
        }
    }

    // ---- Phase 2b: half window-rows ----
    // float4 unit f in 0..1023 per half: j = f>>5, e = f&31, q = e>>1, pp = (e&1)*4.
    // store covers k = q*16 + (pbase+pp) .. +3  (consecutive k increments p).
#pragma unroll
    for (int m2 = 0; m2 < 2; ++m2) {
        const int f  = m2 * 512 + tid;
        const int j  = f >> 5;
        const int e  = f & 31;
        const int q2 = e >> 1;
        const int pp = (e & 1) * 4;

        // upper half of window-row 2g+1: p = pp..pp+3 (<8) <- local rows 8+pp..
        {
            const float* src = &tile[(8 + pp) * LDSW + j * 8 + q2];
            const int n = 64 * g + 32 + j;
            *reinterpret_cast<float4*>(outb + (size_t)n * 256 + q2 * 16 + pp) =
                make_float4(src[0], src[LDSW], src[2 * LDSW], src[3 * LDSW]);
        }
        // lower half of window-row 2g-1: p = 8+pp.. <- local rows pp..
        if (g > 0) {
            const float* src = &tile[pp * LDSW + j * 8 + q2];
            const int n = 64 * g - 32 + j;
            *reinterpret_cast<float4*>(outb + (size_t)n * 256 + q2 * 16 + 8 + pp) =
                make_float4(src[0], src[LDSW], src[2 * LDSW], src[3 * LDSW]);
        }
        // g==15: padding half (p>=8) of window-row 31 <- image rows 256.. = zeros
        if (g == 15) {
            const int n = 992 + j;
            *reinterpret_cast<float4*>(outb + (size_t)n * 256 + q2 * 16 + 8 + pp) =
                make_float4(0.f, 0.f, 0.f, 0.f);
        }
    }
}

} // namespace

extern "C" void kernel_launch(void* const* d_in, const int* in_sizes, int n_in,
                              void* d_out, int out_size, void* d_ws, size_t ws_size,
                              hipStream_t stream) {
    const float* in = (const float*)d_in[0];
    const float* wt = (const float*)d_in[1];
    float* out      = (float*)d_out;
    hipLaunchKernelGGL(meas_kernel, dim3(512), dim3(512), 0, stream, in, wt, out);
}

// Round 10
// 34.635 us; speedup vs baseline: 1.3722x; 1.0837x over previous
//
#include <hip/hip_runtime.h>

// out[b,s,h,w] = sum_t input[b,s,t,h,w] * weight[t, h%8, w%8]   (h,w < 256; else 0)
// output[b, s*1024 + i*32 + j, q*16 + p] = out[b,s, 8i+p, 8j+q]   i,j in [0,32), p,q in [0,16)
//
// Round-10: R9 zero-halo scatter-write + sched_barrier(0) fence between the
// 16-load batch and the FMA loop. R9 counters (VGPR=36, VALUBusy=1.7%) showed
// the compiler sank the v[16] loads into the FMA loop -> ~2 loads in flight.
// The fence forces all 16 1KB wave-bursts issued before any FMA: 16KB/wave in
// flight (verify: VGPR ~100).

namespace {

constexpr int TT   = 16;
constexpr int LDSW = 268;   // 264 cols + 4 pad

__global__ __launch_bounds__(512, 4) void meas_kernel(
    const float* __restrict__ in, const float* __restrict__ wt,
    float* __restrict__ out)
{
    __shared__ float tile[16 * LDSW];
    __shared__ float wlds[TT * 64];

    const int tid = threadIdx.x;
    for (int idx = tid; idx < TT * 64; idx += 512) wlds[idx] = wt[idx];

    // zero halo cols 256..263 (c4 slots 64,65) of the 16 tile rows
    if (tid < 32) {
        const int r  = tid >> 1;
        const int c4 = 64 + (tid & 1);
        *reinterpret_cast<float4*>(&tile[r * LDSW + c4 * 4]) =
            make_float4(0.f, 0.f, 0.f, 0.f);
    }

    // XCD swizzle: 512 blocks, 8 XCDs -> 64 logical blocks (one b) per XCD;
    // g-neighbors (who share output cache lines) adjacent -> co-XCD, co-time.
    const int bid = (blockIdx.x & 7) * 64 + (blockIdx.x >> 3);
    const int g = bid & 15;
    const int s = (bid >> 4) & 3;
    const int b = bid >> 6;

    const float* __restrict__ inp = in + (size_t)(b * 4 + s) * TT * 65536;
    float* __restrict__ outb = out + ((size_t)b * 4096 + (size_t)s * 1024) * 256;

    __syncthreads();   // weights + halo zeros visible

    // ---- Phase 1: t-sum of rows [16g, 16g+16) into LDS ----
    // slot -> r = slot>>6 (wave-uniform), lane c -> w = 4c: per t one aligned
    // contiguous 1KB wave burst. All rows valid: no bounds checks.
#pragma unroll 1
    for (int m = 0; m < 2; ++m) {
        const int slot = m * 512 + tid;
        const int r = slot >> 6;      // 0..15
        const int c = slot & 63;
        const int h = g * 16 + r;
        const int w = c * 4;
        const float* gp = inp + h * 256 + w;

        // 1) issue all 16 strided 1KB bursts back-to-back
        float4 v[TT];
#pragma unroll
        for (int t = 0; t < TT; ++t)
            v[t] = *reinterpret_cast<const float4*>(gp + t * 65536);

        // hard scheduler fence: no FMA may be hoisted above / no load sunk below
        __builtin_amdgcn_sched_barrier(0);

        // 2) FMA against LDS-resident weights
        const float* wrow = &wlds[(h & 7) * 8 + (w & 7)];
        float4 acc = make_float4(0.f, 0.f, 0.f, 0.f);
#pragma unroll
        for (int t = 0; t < TT; ++t) {
            const float4 wv = *reinterpret_cast<const float4*>(wrow + t * 64);
            acc.x += v[t].x * wv.x;
            acc.y += v[t].y * wv.y;
            acc.z += v[t].z * wv.z;
            acc.w += v[t].w * wv.w;
        }
        *reinterpret_cast<float4*>(&tile[r * LDSW + w]) = acc;
    }

    __syncthreads();

    const int wave = tid >> 6;   // 0..7
    const int lane = tid & 63;

    // ---- Phase 2a: full window-row i = 2g (32 windows, 1KB bursts) ----
    // k = 4*lane + jj : p = (lane&3)*4 + jj, q = lane>>2 ; lane*4 == q*16+p0
    {
        const int p0 = (lane & 3) * 4;
        const int q  = lane >> 2;
#pragma unroll
        for (int mm = 0; mm < 4; ++mm) {
            const int j = wave + 8 * mm;                    // 0..31
            const float* src = &tile[p0 * LDSW + j * 8 + q];
            const int n = 64 * g + j;
            *reinterpret_cast<float4*>(outb + (size_t)n * 256 + lane * 4) =
                make_float4(src[0], src[LDSW], src[2 * LDSW], src[3 * LDSW]);
        }
    }

    // ---- Phase 2b: half window-rows ----
    // float4 unit f in 0..1023 per half: j = f>>5, e = f&31, q = e>>1, pp = (e&1)*4.
#pragma unroll
    for (int m2 = 0; m2 < 2; ++m2) {
        const int f  = m2 * 512 + tid;
        const int j  = f >> 5;
        const int e  = f & 31;
        const int q2 = e >> 1;
        const int pp = (e & 1) * 4;

        // upper half of window-row 2g+1: p = pp..pp+3 (<8) <- local rows 8+pp..
        {
            const float* src = &tile[(8 + pp) * LDSW + j * 8 + q2];
            const int n = 64 * g + 32 + j;
            *reinterpret_cast<float4*>(outb + (size_t)n * 256 + q2 * 16 + pp) =
                make_float4(src[0], src[LDSW], src[2 * LDSW], src[3 * LDSW]);
        }
        // lower half of window-row 2g-1: p = 8+pp.. <- local rows pp..
        if (g > 0) {
            const float* src = &tile[pp * LDSW + j * 8 + q2];
            const int n = 64 * g - 32 + j;
            *reinterpret_cast<float4*>(outb + (size_t)n * 256 + q2 * 16 + 8 + pp) =
                make_float4(src[0], src[LDSW], src[2 * LDSW], src[3 * LDSW]);
        }
        // g==15: padding half (p>=8) of window-row 31 <- image rows 256.. = zeros
        if (g == 15) {
            const int n = 992 + j;
            *reinterpret_cast<float4*>(outb + (size_t)n * 256 + q2 * 16 + 8 + pp) =
                make_float4(0.f, 0.f, 0.f, 0.f);
        }
    }
}

} // namespace

extern "C" void kernel_launch(void* const* d_in, const int* in_sizes, int n_in,
                              void* d_out, int out_size, void* d_ws, size_t ws_size,
                              hipStream_t stream) {
    const float* in = (const float*)d_in[0];
    const float* wt = (const float*)d_in[1];
    float* out      = (float*)d_out;
    hipLaunchKernelGGL(meas_kernel, dim3(512), dim3(512), 0, stream, in, wt, out);
}